// Round 1
// 135.358 us; speedup vs baseline: 1.0632x; 1.0632x over previous
//
#include <hip/hip_runtime.h>
#include <hip/hip_bf16.h>

#define NB 32
#define NN 2048
#define DD 64
#define NCH 32
#define LOG2E 1.44269504088896340736f
#define SQC 0.4246613965f  // sqrt(0.125 * LOG2E)

typedef __attribute__((ext_vector_type(8))) short short8;
typedef __attribute__((ext_vector_type(4))) short short4v;
typedef __attribute__((ext_vector_type(4))) float f32x4;

#define MFMA32K(A, B, C) \
  __builtin_amdgcn_mfma_f32_16x16x32_bf16((A), (B), (C), 0, 0, 0)
#define MFMA16(A, B, C) \
  __builtin_amdgcn_mfma_f32_16x16x16bf16_1k((A), (B), (C), 0, 0, 0)

#define GLOAD_LDS16(gp, lp)                                                   \
  __builtin_amdgcn_global_load_lds(                                          \
      (const __attribute__((address_space(1))) void*)(gp),                   \
      (__attribute__((address_space(3))) void*)(lp), 16, 0, 0)

__device__ __forceinline__ short f2bf(float x) {
  __bf16 h = (__bf16)x;
  return __builtin_bit_cast(short, h);
}

__device__ __forceinline__ float fast_exp2(float x) {
#if __has_builtin(__builtin_amdgcn_exp2f)
  return __builtin_amdgcn_exp2f(x);
#else
  return exp2f(x);
#endif
}

// round-to-nearest bf16 pack of two positive floats: lo -> low short
__device__ __forceinline__ unsigned pack_bf16_rnd(float lo, float hi) {
  unsigned ulo = __builtin_bit_cast(unsigned, lo) + 0x8000u;
  unsigned uhi = __builtin_bit_cast(unsigned, hi) + 0x8000u;
  return __builtin_amdgcn_perm(uhi, ulo, 0x07060302u);
}

// ---------- fused prep: fragment-major bf16 image (K units pre-scaled by
// SQC, V units transposed) + adj int32 -> bitmask. adj part is independent
// work appended to the same launch (saves one dispatch in the serial graph).
__global__ __launch_bounds__(256) void prep_fused(
    const float* __restrict__ x, const int* __restrict__ adj,
    short* __restrict__ img, unsigned long long* __restrict__ bits) {
  __shared__ float t[64 * 68];
  const int tid = threadIdx.x;
  const int c = blockIdx.x;
  const int b = blockIdx.y;
  const int r = tid >> 2;
  const int cg = tid & 3;

  const float* src = x + ((size_t)b * NN + c * 64 + r) * DD + cg * 16;
#pragma unroll
  for (int h = 0; h < 4; ++h)
    *(float4*)&t[r * 68 + cg * 16 + h * 4] = ((const float4*)src)[h];
  __syncthreads();

  short* imgc = img + (size_t)(b * NCH + c) * 16 * 512;

  // K units (scaled by SQC)
#pragma unroll
  for (int i = 0; i < 2; ++i) {
    const int kc = tid + i * 256;
    const int u = kc >> 6, l = kc & 63;
    const int nt = u >> 1, ks = u & 1;
    const float* tr = &t[(nt * 16 + (l & 15)) * 68 + ks * 32 + (l >> 4) * 8];
    short8 v;
#pragma unroll
    for (int j = 0; j < 8; ++j) v[j] = f2bf(tr[j] * SQC);
    *(short8*)&imgc[(size_t)u * 512 + l * 8] = v;
  }
  // V units (unscaled, transposed gather)
#pragma unroll
  for (int i = 0; i < 2; ++i) {
    const int vc = tid + i * 256;
    const int u = vc >> 6, l = vc & 63;
    const int dt = u >> 1, ntp = u & 1;
    const int d = dt * 16 + (l & 15);
    const int k0 = ntp * 32 + ((l >> 4) << 2);
    short8 o;
#pragma unroll
    for (int h = 0; h < 2; ++h)
#pragma unroll
      for (int r2 = 0; r2 < 4; ++r2)
        o[h * 4 + r2] = f2bf(t[(k0 + h * 16 + r2) * 68 + d]);
    *(short8*)&imgc[(size_t)(8 + u) * 512 + l * 8] = o;
  }

  // adj -> bitmask: 1024 blocks x 256 threads, 16 entries/thread
  const int base = (b * NCH + c) * 4096;
#pragma unroll
  for (int k = 0; k < 16; ++k) {
    const int idx = base + k * 256 + tid;
    unsigned long long m = __ballot(adj[idx] > 0);
    if ((tid & 63) == 0) bits[idx >> 6] = m;
  }
}

// one chunk's compute: 1 Q-tile (16 rows) per wave, 64 keys
__device__ __forceinline__ void chunk_body(
    const short* __restrict__ sB, unsigned long long a, int quad, int l,
    const short8 (&qf)[2], const short4v& ones, f32x4 (&acc)[4], f32x4& acl) {
  a >>= (quad * 4);
  const unsigned lo = (unsigned)a, hi = (unsigned)(a >> 32);
  const short* sK = sB;
  const short* sV = sB + 4096;

#pragma unroll
  for (int ntp = 0; ntp < 2; ++ntp) {
    short4v pf[2];  // [h]
#pragma unroll
    for (int h = 0; h < 2; ++h) {
      const int nt = ntp * 2 + h;
      f32x4 s = {0.f, 0.f, 0.f, 0.f};
#pragma unroll
      for (int ks = 0; ks < 2; ++ks) {
        short8 kf = *(const short8*)&sK[(nt * 2 + ks) * 512 + l * 8];
        s = MFMA32K(kf, qf[ks], s);
      }
      const unsigned wm = (nt < 2) ? lo : hi;
      const int sh = (nt & 1) * 16;
      float p[4];
#pragma unroll
      for (int r = 0; r < 4; ++r) {
        float e = fast_exp2(s[r]);
        p[r] = ((wm >> (sh + r)) & 1u) ? e : 0.f;
      }
      uint2 u;
      u.x = pack_bf16_rnd(p[0], p[1]);
      u.y = pack_bf16_rnd(p[2], p[3]);
      pf[h] = __builtin_bit_cast(short4v, u);
      acl = MFMA16(ones, pf[h], acl);
    }
#pragma unroll
    for (int dt = 0; dt < 4; ++dt) {
      short8 vv = *(const short8*)&sV[(dt * 2 + ntp) * 512 + l * 8];
      short4v vlo, vhi;
      vlo[0] = vv[0]; vlo[1] = vv[1]; vlo[2] = vv[2]; vlo[3] = vv[3];
      vhi[0] = vv[4]; vhi[1] = vv[5]; vhi[2] = vv[6]; vhi[3] = vv[7];
      acc[dt] = MFMA16(vlo, pf[0], acc[dt]);
      acc[dt] = MFMA16(vhi, pf[1], acc[dt]);
    }
  }
}

// ---------- main: single chunk-stream, 32 KB LDS, 4 blocks/CU (TLP replaces
// the old dual-stream ILP). 1024 blocks = 8 XCD x 4 batches x 32 q-groups;
// beta&7 = XCD so each XCD keeps 4 batches' img (~2.1 MB) L2-resident.
__global__ __launch_bounds__(256, 4) void gat_flash9(
    const short* __restrict__ img, const unsigned long long* __restrict__ adjb,
    float* __restrict__ out) {
  __shared__ short sI[2][8192];  // double-buffered 16 KB chunk

  const int beta = blockIdx.x;
  const int xcd = beta & 7;
  const int idx = beta >> 3;        // 0..127
  const int xq = idx & 31;          // 64-row q-group
  const int b = xcd * 4 + (idx >> 5);

  const int tid = threadIdx.x;
  const int w = tid >> 6;
  const int l = tid & 63;
  const int lane16 = l & 15;
  const int quad = l >> 4;

  const short* img_b = img + (size_t)b * NCH * 16 * 512;

  // Q B-frags straight from the pre-scaled img K-units of q-chunk xq;
  // wave w owns 16-row tile nt=w of that chunk.
  short8 qf[2];
#pragma unroll
  for (int ks = 0; ks < 2; ++ks)
    qf[ks] =
        *(const short8*)&img_b[((size_t)xq * 16 + w * 2 + ks) * 512 + l * 8];

  f32x4 acc[4];
  f32x4 acl = {0.f, 0.f, 0.f, 0.f};
#pragma unroll
  for (int dt = 0; dt < 4; ++dt) acc[dt] = {0.f, 0.f, 0.f, 0.f};

  short4v ones;
  ones[0] = 0x3F80; ones[1] = 0x3F80; ones[2] = 0x3F80; ones[3] = 0x3F80;

  const unsigned long long* ar =
      adjb + (size_t)(xq * 64 + w * 16 + lane16) * NCH;

#pragma unroll
  for (int i = 0; i < 4; ++i) {
    const int u = i * 4 + w;
    GLOAD_LDS16(img_b + (size_t)u * 512 + l * 8, &sI[0][u * 512]);
  }
  __syncthreads();

#pragma unroll 2
  for (int c = 0; c < 32; ++c) {
    const int cur = c & 1;
    if (c < 31) {
      const short* p = img_b + (size_t)(c + 1) * 8192;
#pragma unroll
      for (int i = 0; i < 4; ++i) {
        const int u = i * 4 + w;
        GLOAD_LDS16(p + (size_t)u * 512 + l * 8, &sI[cur ^ 1][u * 512]);
      }
    }
    chunk_body(sI[cur], ar[c], quad, l, qf, ones, acc, acl);
    __syncthreads();
  }

  // ---- epilogue ----
  const float inv = 1.0f / acl[0];
  float* op =
      out + ((size_t)b * NN + xq * 64 + w * 16 + lane16) * DD + quad * 4;
#pragma unroll
  for (int dt = 0; dt < 4; ++dt) {
    float4 o;
    o.x = acc[dt][0] * inv;
    o.y = acc[dt][1] * inv;
    o.z = acc[dt][2] * inv;
    o.w = acc[dt][3] * inv;
    *(float4*)(op + dt * 16) = o;
  }
}

extern "C" void kernel_launch(void* const* d_in, const int* in_sizes, int n_in,
                              void* d_out, int out_size, void* d_ws,
                              size_t ws_size, hipStream_t stream) {
  const float* x = (const float*)d_in[0];
  const int* adj = (const int*)d_in[1];
  float* out = (float*)d_out;

  short* img = (short*)d_ws;  // 16 MB fragment-major image
  unsigned long long* adjb =
      (unsigned long long*)(img + (size_t)NB * NCH * 16 * 512);  // 512 KB

  prep_fused<<<dim3(NCH, NB), 256, 0, stream>>>(x, adj, img, adjb);
  gat_flash9<<<1024, 256, 0, stream>>>(img, adjb, out);
}